// Round 13
// baseline (156.517 us; speedup 1.0000x reference)
//
#include <hip/hip_runtime.h>

typedef float f32x4 __attribute__((ext_vector_type(4)));
typedef short bf16x8 __attribute__((ext_vector_type(8)));

__device__ __forceinline__ unsigned short f2bf(float f) {
  unsigned u = __builtin_bit_cast(unsigned, f);
  u = (u + 0x7FFFu + ((u >> 16) & 1u)) >> 16;
  return (unsigned short)u;
}

// async global->LDS, 16B per lane. Dest param = wave-uniform base; HW adds lane*16B.
__device__ __forceinline__ void async16(const unsigned short* g, unsigned short* l) {
  __builtin_amdgcn_global_load_lds(
      (__attribute__((address_space(1))) void*)g,
      (__attribute__((address_space(3))) void*)l, 16, 0, 0);
}

// xt padded layout: [b][row 0..129][col 0..129][ch 0..127] bf16, borders zero.
#define XT_ROW 16640              // 130*128 elems per padded row

// ---------------------------------------------------------------------------
// Kernel 1: x (B,C,H,W) f32 -> xt padded bf16 [b][y+1][col+1][c], + row sums
// ---------------------------------------------------------------------------
__global__ __launch_bounds__(256) void k_transpose(const float* __restrict__ x,
                                                   unsigned short* __restrict__ xt,
                                                   float* __restrict__ rowsum) {
  __shared__ unsigned short tile[128][128];
  __shared__ float psum[128][8];
  const int y = blockIdx.x, b = blockIdx.y;
  const int t = threadIdx.x;
  const int colb = (t & 7) * 16;
  const int cp = t >> 3;
  const int swz = (t & 7) << 3;
  for (int ci = 0; ci < 4; ++ci) {
    const int c = ci * 32 + cp;
    const int c2 = c ^ swz;
    const float* src = x + (((size_t)(b * 128 + c) * 128 + y) * 128 + colb);
    float s = 0.f;
#pragma unroll
    for (int j = 0; j < 16; j += 4) {
      float4 v = *(const float4*)(src + j);
      s += v.x + v.y + v.z + v.w;
      tile[colb + j + 0][c2] = f2bf(v.x);
      tile[colb + j + 1][c2] = f2bf(v.y);
      tile[colb + j + 2][c2] = f2bf(v.z);
      tile[colb + j + 3][c2] = f2bf(v.w);
    }
    psum[c][t & 7] = s;
  }
  __syncthreads();
#pragma unroll
  for (int it = 0; it < 8; ++it) {
    const int slot = t + it * 256;
    const int col = slot >> 4;
    const int cg = (slot & 15) * 8;
    const int c2 = cg ^ (((col >> 4) & 7) << 3);
    uint4 vv = *(const uint4*)&tile[col][c2];
    *(uint4*)(xt + (((size_t)b * 130 + y + 1) * 130 + col + 1) * 128 + cg) = vv;
  }
  if (t < 128) {
    float r = 0.f;
#pragma unroll
    for (int j = 0; j < 8; ++j) r += psum[t][j];
    rowsum[((size_t)b * 128 + t) * 128 + y] = r;
  }
}

// ---------------------------------------------------------------------------
// Kernel 1b: zero the padded borders of xt
// ---------------------------------------------------------------------------
__global__ __launch_bounds__(256) void k_border(unsigned short* __restrict__ xt) {
  const int b = blockIdx.y;
  const int idx = blockIdx.x * 256 + threadIdx.x;
  if (idx >= 8256) return;
  int row, col, ck;
  if (idx < 4160) {
    row = (idx < 2080) ? 0 : 129;
    const int s = idx % 2080;
    col = s >> 4;
    ck = s & 15;
  } else {
    const int s = idx - 4160;
    row = (s >> 5) + 1;
    col = (s & 16) ? 129 : 0;
    ck = s & 15;
  }
  uint4 z = {0, 0, 0, 0};
  *(uint4*)(xt + ((size_t)b * 130 + row) * 130 * 128 + (size_t)col * 128 + ck * 8) = z;
}

// ---------------------------------------------------------------------------
// Kernel 2: rowsums -> pooled -> attention MLP -> softmax -> attn, agg_b
// ---------------------------------------------------------------------------
__global__ __launch_bounds__(128) void k_attn(const float* __restrict__ rowsum,
                                              const float* __restrict__ aw1,
                                              const float* __restrict__ ab1,
                                              const float* __restrict__ aw2,
                                              const float* __restrict__ ab2,
                                              const float* __restrict__ bias,
                                              float* __restrict__ attn,
                                              float* __restrict__ aggb) {
  __shared__ float pooled[128];
  __shared__ float h[32];
  __shared__ float at[4];
  const int b = blockIdx.x, t = threadIdx.x;
  const float* rs = rowsum + (size_t)(b * 128 + t) * 128;
  float s = 0.f;
  for (int yy = 0; yy < 128; ++yy) s += rs[yy];
  pooled[t] = s * (1.f / 16384.f);
  __syncthreads();
  if (t < 32) {
    float hv = ab1[t];
    for (int c = 0; c < 128; ++c) hv += pooled[c] * aw1[t * 128 + c];
    h[t] = fmaxf(hv, 0.f);
  }
  __syncthreads();
  if (t < 4) {
    float sc = ab2[t];
    for (int a = 0; a < 32; ++a) sc += h[a] * aw2[t * 32 + a];
    at[t] = sc * (1.f / 30.f);
  }
  __syncthreads();
  if (t == 0) {
    float m = fmaxf(fmaxf(at[0], at[1]), fmaxf(at[2], at[3]));
    float e0 = __expf(at[0] - m), e1 = __expf(at[1] - m);
    float e2 = __expf(at[2] - m), e3 = __expf(at[3] - m);
    float inv = 1.f / (e0 + e1 + e2 + e3);
    at[0] = e0 * inv; at[1] = e1 * inv; at[2] = e2 * inv; at[3] = e3 * inv;
  }
  __syncthreads();
  if (t < 4) attn[b * 4 + t] = at[t];
  float ab = 0.f;
  for (int k = 0; k < 4; ++k) ab += at[k] * bias[k * 128 + t];
  aggb[b * 128 + t] = ab;
}

// ---------------------------------------------------------------------------
// Kernel 3: aggregate weights over K, bf16, slab layout for BK=32:
//   aggw[(((b*36 + s)*128 + o)*32 + kk)], tap = s>>2, c = (s&3)*32 + kk
// ---------------------------------------------------------------------------
__global__ __launch_bounds__(256) void k_aggw(const float* __restrict__ weight,
                                              const float* __restrict__ attn,
                                              unsigned short* __restrict__ aggw) {
  const int fid = blockIdx.x * 256 + threadIdx.x;
  const int kk = fid & 31;
  const int o = (fid >> 5) & 127;
  const int rest = fid >> 12;      // b*36 + s
  const int s = rest % 36;
  const int b = rest / 36;
  const int c = ((s & 3) << 5) + kk;
  const int pq = s >> 2;
  const size_t src = (size_t)o * 1152 + (size_t)c * 9 + pq;
  float v = attn[b * 4 + 0] * weight[src]
          + attn[b * 4 + 1] * weight[src + 147456]
          + attn[b * 4 + 2] * weight[src + 2 * 147456]
          + attn[b * 4 + 3] * weight[src + 3 * 147456];
  aggw[fid] = f2bf(v);
}

// ---------------------------------------------------------------------------
// Kernel 4: conv implicit GEMM. Per-wave 128x64 output tile, BK=32, 36 tiles.
// BM=128(Cout) x BN=512 (4 y-rows x 128 cols). 512 thr / 8 N-waves.
// TRI-buffer LDS 120KB (3 x (A[128][32] + B[512][32])), stage 2 TILES AHEAD,
// boundary s_waitcnt vmcnt(5): drains only loads issued ~2 tiles (~3500cyc)
// earlier -- the r7-r12 plateau was the boundary drain of just-issued loads.
// 2 phases/tile x 16 MFMA. Granule-spread XOR swizzle ((row>>1)&3) both sides.
// ---------------------------------------------------------------------------
__global__ __launch_bounds__(512, 2) void k_conv(const unsigned short* __restrict__ xt,
                                                 const unsigned short* __restrict__ aggw,
                                                 const float* __restrict__ aggb,
                                                 float* __restrict__ out) {
  __shared__ unsigned short lds[61440];  // 3 bufs x 20480 elems (A@0, B@4096)
  const int id = blockIdx.x;
  const int swz = (id & 7) * 64 + (id >> 3);   // 512 % 8 == 0: bijective
  const int b = swz >> 5;
  const int Y = (swz & 31) * 4;           // output y-quad base
  const int t = threadIdx.x;
  const int lane = t & 63, nw = t >> 6, w = t >> 6;
  const int l15 = lane & 15, lk = lane >> 4;
  const int xc = (lk ^ ((l15 >> 1) & 3)) * 8;   // granule-spread XOR (elems)
  const int aBase = l15 * 32 + xc;              // + mi*512
  const int nrow = (nw >> 1) * 128 + (nw & 1) * 64 + l15;
  const int bBase = 4096 + nrow * 32 + xc;      // + ni*512

  // ---- staging sources (source-side XOR; LDS dest linear) -----------------
  // A: 512 chunks, 1/thread: o = t>>2, k8 = t&3
  const unsigned short* aS;
  {
    const int o = t >> 2, k8 = t & 3;
    aS = aggw + (size_t)b * 147456 + o * 32 + ((k8 ^ ((o >> 1) & 3)) * 8);
  }
  // B: 2048 chunks, 4/thread: c = i*512+t -> n = c>>2, k8 = c&3
  const unsigned short* bS[4];
#pragma unroll
  for (int i = 0; i < 4; ++i) {
    const int c = i * 512 + t, n = c >> 2, k8 = c & 3;
    const int r = n >> 7, col = n & 127;
    bS[i] = xt + ((size_t)(b * 130 + Y + r) * 130 + col) * 128
          + ((k8 ^ ((n >> 1) & 3)) * 8);
  }

#define STA(jb, sv) async16(aS + (size_t)(sv) * 4096, &lds[(jb) + w * 512])
#define STB(jb, bo, i) async16(bS[i] + (bo), &lds[(jb) + 4096 + ((i) * 512 + w * 64) * 8])
#define BOFF(sv) (((sv) >> 2) / 3 * XT_ROW + (((sv) >> 2) - 3 * (((sv) >> 2) / 3)) * 128 \
                  + (((sv) & 3) << 5))

  // prologue: stage tiles 0 and 1
  STA(0, 0);
#pragma unroll
  for (int i = 0; i < 4; ++i) STB(0, BOFF(0), i);
  STA(20480, 1);
#pragma unroll
  for (int i = 0; i < 4; ++i) STB(20480, BOFF(1), i);

  f32x4 acc[8][4] = {};

#pragma unroll
  for (int s = 0; s < 36; ++s) {
    const int jb = (s % 3) * 20480;
    const int j2 = ((s + 2) % 3) * 20480;
    const int s2 = s + 2;
    const bool st = (s2 < 36);
    const int bo2 = st ? BOFF(s2) : 0;

    // ---- tile boundary: counted vmcnt (T4) --------------------------------
    if (s < 35) { asm volatile("s_waitcnt vmcnt(5)" ::: "memory"); }
    else        { asm volatile("s_waitcnt vmcnt(0)" ::: "memory"); }
    __builtin_amdgcn_sched_barrier(0);
    __builtin_amdgcn_s_barrier();
    __builtin_amdgcn_sched_barrier(0);
    if (st) { STA(j2, s2); STB(j2, bo2, 0); STB(j2, bo2, 1); }

    bf16x8 a0, a1, a2, a3, b0, b1, b2, b3;
    // ---- phase 0: B0-3 + A0-3; 16 MFMA ------------------------------------
    b0 = *(const bf16x8*)(&lds[jb + bBase + 0 * 512]);
    b1 = *(const bf16x8*)(&lds[jb + bBase + 1 * 512]);
    b2 = *(const bf16x8*)(&lds[jb + bBase + 2 * 512]);
    b3 = *(const bf16x8*)(&lds[jb + bBase + 3 * 512]);
    a0 = *(const bf16x8*)(&lds[jb + aBase + 0 * 512]);
    a1 = *(const bf16x8*)(&lds[jb + aBase + 1 * 512]);
    a2 = *(const bf16x8*)(&lds[jb + aBase + 2 * 512]);
    a3 = *(const bf16x8*)(&lds[jb + aBase + 3 * 512]);
    __builtin_amdgcn_sched_barrier(0);
    __builtin_amdgcn_s_barrier();
    __builtin_amdgcn_sched_barrier(0);
    __builtin_amdgcn_s_setprio(1);
#pragma unroll
    for (int ni = 0; ni < 4; ++ni) {
      const bf16x8 bb = (ni == 0) ? b0 : (ni == 1) ? b1 : (ni == 2) ? b2 : b3;
      acc[0][ni] = __builtin_amdgcn_mfma_f32_16x16x32_bf16(a0, bb, acc[0][ni], 0, 0, 0);
      acc[1][ni] = __builtin_amdgcn_mfma_f32_16x16x32_bf16(a1, bb, acc[1][ni], 0, 0, 0);
      acc[2][ni] = __builtin_amdgcn_mfma_f32_16x16x32_bf16(a2, bb, acc[2][ni], 0, 0, 0);
      acc[3][ni] = __builtin_amdgcn_mfma_f32_16x16x32_bf16(a3, bb, acc[3][ni], 0, 0, 0);
    }
    __builtin_amdgcn_s_setprio(0);
    __builtin_amdgcn_s_barrier();
    // ---- phase 1: A4-7; 16 MFMA; stage rest of tile s+2 -------------------
    a0 = *(const bf16x8*)(&lds[jb + aBase + 4 * 512]);
    a1 = *(const bf16x8*)(&lds[jb + aBase + 5 * 512]);
    a2 = *(const bf16x8*)(&lds[jb + aBase + 6 * 512]);
    a3 = *(const bf16x8*)(&lds[jb + aBase + 7 * 512]);
    if (st) { STB(j2, bo2, 2); STB(j2, bo2, 3); }
    __builtin_amdgcn_sched_barrier(0);
    __builtin_amdgcn_s_barrier();
    __builtin_amdgcn_sched_barrier(0);
    __builtin_amdgcn_s_setprio(1);
#pragma unroll
    for (int ni = 0; ni < 4; ++ni) {
      const bf16x8 bb = (ni == 0) ? b0 : (ni == 1) ? b1 : (ni == 2) ? b2 : b3;
      acc[4][ni] = __builtin_amdgcn_mfma_f32_16x16x32_bf16(a0, bb, acc[4][ni], 0, 0, 0);
      acc[5][ni] = __builtin_amdgcn_mfma_f32_16x16x32_bf16(a1, bb, acc[5][ni], 0, 0, 0);
      acc[6][ni] = __builtin_amdgcn_mfma_f32_16x16x32_bf16(a2, bb, acc[6][ni], 0, 0, 0);
      acc[7][ni] = __builtin_amdgcn_mfma_f32_16x16x32_bf16(a3, bb, acc[7][ni], 0, 0, 0);
    }
    __builtin_amdgcn_s_setprio(0);
    // (next tile's boundary barrier closes this phase)
  }
#undef STA
#undef STB
#undef BOFF

  // epilogue: wave nw: y = Y + (nw>>1), colb = (nw&1)*64 + l15
  const int y = Y + (nw >> 1);
  const int colb = (nw & 1) * 64 + l15;
#pragma unroll
  for (int mi = 0; mi < 8; ++mi) {
    const int o = mi * 16 + lk * 4;
#pragma unroll
    for (int rr = 0; rr < 4; ++rr) {
      const float bsv = aggb[b * 128 + o + rr];
      float* orow = out + ((size_t)(b * 128 + o + rr) * 128 + y) * 128 + colb;
      orow[0]  = acc[mi][0][rr] + bsv;
      orow[16] = acc[mi][1][rr] + bsv;
      orow[32] = acc[mi][2][rr] + bsv;
      orow[48] = acc[mi][3][rr] + bsv;
    }
  }
}

// ---------------------------------------------------------------------------
extern "C" void kernel_launch(void* const* d_in, const int* in_sizes, int n_in,
                              void* d_out, int out_size, void* d_ws, size_t ws_size,
                              hipStream_t stream) {
  const float* x      = (const float*)d_in[0];
  const float* weight = (const float*)d_in[1];
  const float* bias   = (const float*)d_in[2];
  const float* aw1    = (const float*)d_in[3];
  const float* ab1    = (const float*)d_in[4];
  const float* aw2    = (const float*)d_in[5];
  const float* ab2    = (const float*)d_in[6];
  float* out = (float*)d_out;

  char* ws = (char*)d_ws;
  unsigned short* xt   = (unsigned short*)ws;                        // 69,222,400 B
  unsigned short* aggw = (unsigned short*)(ws + 69222400);           //  4,718,592 B
  float* rowsum        = (float*)(ws + 69222400 + 4718592);          //  1,048,576 B
  float* attn          = (float*)(ws + 69222400 + 4718592 + 1048576);         // 256 B
  float* aggb          = (float*)(ws + 69222400 + 4718592 + 1048576 + 256);   // 8 KB

  hipLaunchKernelGGL(k_border, dim3(33, 16), dim3(256), 0, stream, xt);
  hipLaunchKernelGGL(k_transpose, dim3(128, 16), dim3(256), 0, stream, x, xt, rowsum);
  hipLaunchKernelGGL(k_attn, dim3(16), dim3(128), 0, stream,
                     rowsum, aw1, ab1, aw2, ab2, bias, attn, aggb);
  hipLaunchKernelGGL(k_aggw, dim3(9216), dim3(256), 0, stream, weight, attn, aggw);
  hipLaunchKernelGGL(k_conv, dim3(512), dim3(512), 0, stream, xt, aggw, aggb, out);
}

// Round 14
// 155.142 us; speedup vs baseline: 1.0089x; 1.0089x over previous
//
#include <hip/hip_runtime.h>

typedef float f32x4 __attribute__((ext_vector_type(4)));
typedef short bf16x8 __attribute__((ext_vector_type(8)));

__device__ __forceinline__ unsigned short f2bf(float f) {
  unsigned u = __builtin_bit_cast(unsigned, f);
  u = (u + 0x7FFFu + ((u >> 16) & 1u)) >> 16;
  return (unsigned short)u;
}

// async global->LDS, 16B per lane. Dest param = wave-uniform base; HW adds lane*16B.
__device__ __forceinline__ void async16(const unsigned short* g, unsigned short* l) {
  __builtin_amdgcn_global_load_lds(
      (__attribute__((address_space(1))) void*)g,
      (__attribute__((address_space(3))) void*)l, 16, 0, 0);
}

// xt padded layout: [b][row 0..129][col 0..129][ch 0..127] bf16, borders zero.
#define XT_ROW 16640              // 130*128 elems per padded row

// ---------------------------------------------------------------------------
// Kernel 1: x (B,C,H,W) f32 -> xt padded bf16 [b][y+1][col+1][c], + row sums
// ---------------------------------------------------------------------------
__global__ __launch_bounds__(256) void k_transpose(const float* __restrict__ x,
                                                   unsigned short* __restrict__ xt,
                                                   float* __restrict__ rowsum) {
  __shared__ unsigned short tile[128][128];
  __shared__ float psum[128][8];
  const int y = blockIdx.x, b = blockIdx.y;
  const int t = threadIdx.x;
  const int colb = (t & 7) * 16;
  const int cp = t >> 3;
  const int swz = (t & 7) << 3;
  for (int ci = 0; ci < 4; ++ci) {
    const int c = ci * 32 + cp;
    const int c2 = c ^ swz;
    const float* src = x + (((size_t)(b * 128 + c) * 128 + y) * 128 + colb);
    float s = 0.f;
#pragma unroll
    for (int j = 0; j < 16; j += 4) {
      float4 v = *(const float4*)(src + j);
      s += v.x + v.y + v.z + v.w;
      tile[colb + j + 0][c2] = f2bf(v.x);
      tile[colb + j + 1][c2] = f2bf(v.y);
      tile[colb + j + 2][c2] = f2bf(v.z);
      tile[colb + j + 3][c2] = f2bf(v.w);
    }
    psum[c][t & 7] = s;
  }
  __syncthreads();
#pragma unroll
  for (int it = 0; it < 8; ++it) {
    const int slot = t + it * 256;
    const int col = slot >> 4;
    const int cg = (slot & 15) * 8;
    const int c2 = cg ^ (((col >> 4) & 7) << 3);
    uint4 vv = *(const uint4*)&tile[col][c2];
    *(uint4*)(xt + (((size_t)b * 130 + y + 1) * 130 + col + 1) * 128 + cg) = vv;
  }
  if (t < 128) {
    float r = 0.f;
#pragma unroll
    for (int j = 0; j < 8; ++j) r += psum[t][j];
    rowsum[((size_t)b * 128 + t) * 128 + y] = r;
  }
}

// ---------------------------------------------------------------------------
// Kernel 1b: zero the padded borders of xt
// ---------------------------------------------------------------------------
__global__ __launch_bounds__(256) void k_border(unsigned short* __restrict__ xt) {
  const int b = blockIdx.y;
  const int idx = blockIdx.x * 256 + threadIdx.x;
  if (idx >= 8256) return;
  int row, col, ck;
  if (idx < 4160) {
    row = (idx < 2080) ? 0 : 129;
    const int s = idx % 2080;
    col = s >> 4;
    ck = s & 15;
  } else {
    const int s = idx - 4160;
    row = (s >> 5) + 1;
    col = (s & 16) ? 129 : 0;
    ck = s & 15;
  }
  uint4 z = {0, 0, 0, 0};
  *(uint4*)(xt + ((size_t)b * 130 + row) * 130 * 128 + (size_t)col * 128 + ck * 8) = z;
}

// ---------------------------------------------------------------------------
// Kernel 2: rowsums -> pooled -> attention MLP -> softmax -> attn, agg_b
// ---------------------------------------------------------------------------
__global__ __launch_bounds__(128) void k_attn(const float* __restrict__ rowsum,
                                              const float* __restrict__ aw1,
                                              const float* __restrict__ ab1,
                                              const float* __restrict__ aw2,
                                              const float* __restrict__ ab2,
                                              const float* __restrict__ bias,
                                              float* __restrict__ attn,
                                              float* __restrict__ aggb) {
  __shared__ float pooled[128];
  __shared__ float h[32];
  __shared__ float at[4];
  const int b = blockIdx.x, t = threadIdx.x;
  const float* rs = rowsum + (size_t)(b * 128 + t) * 128;
  float s = 0.f;
  for (int yy = 0; yy < 128; ++yy) s += rs[yy];
  pooled[t] = s * (1.f / 16384.f);
  __syncthreads();
  if (t < 32) {
    float hv = ab1[t];
    for (int c = 0; c < 128; ++c) hv += pooled[c] * aw1[t * 128 + c];
    h[t] = fmaxf(hv, 0.f);
  }
  __syncthreads();
  if (t < 4) {
    float sc = ab2[t];
    for (int a = 0; a < 32; ++a) sc += h[a] * aw2[t * 32 + a];
    at[t] = sc * (1.f / 30.f);
  }
  __syncthreads();
  if (t == 0) {
    float m = fmaxf(fmaxf(at[0], at[1]), fmaxf(at[2], at[3]));
    float e0 = __expf(at[0] - m), e1 = __expf(at[1] - m);
    float e2 = __expf(at[2] - m), e3 = __expf(at[3] - m);
    float inv = 1.f / (e0 + e1 + e2 + e3);
    at[0] = e0 * inv; at[1] = e1 * inv; at[2] = e2 * inv; at[3] = e3 * inv;
  }
  __syncthreads();
  if (t < 4) attn[b * 4 + t] = at[t];
  float ab = 0.f;
  for (int k = 0; k < 4; ++k) ab += at[k] * bias[k * 128 + t];
  aggb[b * 128 + t] = ab;
}

// ---------------------------------------------------------------------------
// Kernel 3: aggregate weights over K, bf16, slab layout for BK=32:
//   aggw[(((b*36 + s)*128 + o)*32 + kk)], tap = s>>2, c = (s&3)*32 + kk
// ---------------------------------------------------------------------------
__global__ __launch_bounds__(256) void k_aggw(const float* __restrict__ weight,
                                              const float* __restrict__ attn,
                                              unsigned short* __restrict__ aggw) {
  const int fid = blockIdx.x * 256 + threadIdx.x;
  const int kk = fid & 31;
  const int o = (fid >> 5) & 127;
  const int rest = fid >> 12;      // b*36 + s
  const int s = rest % 36;
  const int b = rest / 36;
  const int c = ((s & 3) << 5) + kk;
  const int pq = s >> 2;
  const size_t src = (size_t)o * 1152 + (size_t)c * 9 + pq;
  float v = attn[b * 4 + 0] * weight[src]
          + attn[b * 4 + 1] * weight[src + 147456]
          + attn[b * 4 + 2] * weight[src + 2 * 147456]
          + attn[b * 4 + 3] * weight[src + 3 * 147456];
  aggw[fid] = f2bf(v);
}

// ---------------------------------------------------------------------------
// Kernel 4: conv implicit GEMM — max cross-block overlap variant.
// BM=128(Cout) x BN=128(1 y-row), BK=32, 36 tiles. 256 thr / 4 waves (2x2),
// wave tile 64x64 (16 MFMA / 8 ds_read per tile). Double-buffer LDS 32 KB +
// __launch_bounds__(256,4) -> 4 blocks/CU (16 waves): foreign blocks absorb
// per-phase stalls (m97 implicit-overlap mechanism; best round r6 had 3).
// Guide-minimal 2-phase loop: STAGE(next) -> ds_read -> MFMA -> vmcnt(0)+bar.
// r13's verified conflict-free granule XOR (source-side, zero VALU).
// ---------------------------------------------------------------------------
__global__ __launch_bounds__(256, 4) void k_conv(const unsigned short* __restrict__ xt,
                                                 const unsigned short* __restrict__ aggw,
                                                 const float* __restrict__ aggb,
                                                 float* __restrict__ out) {
  __shared__ unsigned short lds[2][8192];   // per buf: A[128][32] @0, B[128][32] @4096
  const int id = blockIdx.x;
  const int swz = (id & 7) * 256 + (id >> 3);   // 2048 % 8 == 0: bijective
  const int b = swz >> 7, y = swz & 127;
  const int t = threadIdx.x;
  const int lane = t & 63, w = t >> 6;
  const int mw = w >> 1, nw = w & 1;
  const int l15 = lane & 15, lk = lane >> 4;
  const int xc = (lk ^ ((l15 >> 1) & 3)) * 8;   // read-side XOR (elems), per-lane const
  const int aBase = mw * 2048 + l15 * 32 + xc;  // + mi*512
  const int bBase = 4096 + nw * 2048 + l15 * 32 + xc;  // + ni*512

  // ---- staging: A 512 chunks (2/thread), B 512 chunks (2/thread) ----------
  const unsigned short* aS[2];
  const unsigned short* bS[2];
  int dA[2], dB[2];
#pragma unroll
  for (int i = 0; i < 2; ++i) {
    const int c = i * 256 + t, n = c >> 2, k8 = c & 3;
    const int sk = (k8 ^ ((n >> 1) & 3)) * 8;   // inverse-swizzled source slot
    aS[i] = aggw + (size_t)b * 147456 + n * 32 + sk;
    bS[i] = xt + ((size_t)(b * 130 + y) * 130 + n) * 128 + sk;
    dA[i] = i * 2048 + w * 512;                 // wave-uniform dest (elems)
    dB[i] = 4096 + i * 2048 + w * 512;
  }

#define STAGE(buf, s) {                                                        \
    const int tap_ = (s) >> 2, c0_ = ((s) & 3) << 5;                           \
    const int p_ = tap_ / 3, q_ = tap_ - 3 * p_;                               \
    async16(aS[0] + (s) * 4096, &lds[buf][0] + dA[0]);                         \
    async16(aS[1] + (s) * 4096, &lds[buf][0] + dA[1]);                         \
    async16(bS[0] + p_ * XT_ROW + q_ * 128 + c0_, &lds[buf][0] + dB[0]);       \
    async16(bS[1] + p_ * XT_ROW + q_ * 128 + c0_, &lds[buf][0] + dB[1]);       \
  }

  f32x4 acc[4][4] = {};
  STAGE(0, 0);
  asm volatile("s_waitcnt vmcnt(0)" ::: "memory");
  __builtin_amdgcn_s_barrier();

#pragma unroll
  for (int s = 0; s < 36; ++s) {
    const int cur = s & 1;
    if (s + 1 < 36) STAGE(cur ^ 1, s + 1);

    const unsigned short* L = &lds[cur][0];
    bf16x8 af[4], bfr[4];
#pragma unroll
    for (int mi = 0; mi < 4; ++mi)
      af[mi] = *(const bf16x8*)(L + aBase + mi * 512);
#pragma unroll
    for (int ni = 0; ni < 4; ++ni)
      bfr[ni] = *(const bf16x8*)(L + bBase + ni * 512);

    __builtin_amdgcn_s_setprio(1);
#pragma unroll
    for (int mi = 0; mi < 4; ++mi)
#pragma unroll
      for (int ni = 0; ni < 4; ++ni)
        acc[mi][ni] = __builtin_amdgcn_mfma_f32_16x16x32_bf16(af[mi], bfr[ni], acc[mi][ni], 0, 0, 0);
    __builtin_amdgcn_s_setprio(0);

    // end-of-iter sync: drains the 4 loads issued at the TOP of this iter
    // (covered by 8 ds_read + 16 MFMA) and publishes the next buffer.
    asm volatile("s_waitcnt vmcnt(0)" ::: "memory");
    __builtin_amdgcn_sched_barrier(0);
    __builtin_amdgcn_s_barrier();
    __builtin_amdgcn_sched_barrier(0);
  }
#undef STAGE

  // epilogue: C/D col = lane&15 (n/px), row = (lane>>4)*4 + r (Cout)
  const int colb = nw * 64 + l15;
#pragma unroll
  for (int mi = 0; mi < 4; ++mi) {
    const int o = mw * 64 + mi * 16 + lk * 4;
#pragma unroll
    for (int rr = 0; rr < 4; ++rr) {
      const float bsv = aggb[b * 128 + o + rr];
      float* orow = out + ((size_t)(b * 128 + o + rr) * 128 + y) * 128 + colb;
      orow[0]  = acc[mi][0][rr] + bsv;
      orow[16] = acc[mi][1][rr] + bsv;
      orow[32] = acc[mi][2][rr] + bsv;
      orow[48] = acc[mi][3][rr] + bsv;
    }
  }
}

// ---------------------------------------------------------------------------
extern "C" void kernel_launch(void* const* d_in, const int* in_sizes, int n_in,
                              void* d_out, int out_size, void* d_ws, size_t ws_size,
                              hipStream_t stream) {
  const float* x      = (const float*)d_in[0];
  const float* weight = (const float*)d_in[1];
  const float* bias   = (const float*)d_in[2];
  const float* aw1    = (const float*)d_in[3];
  const float* ab1    = (const float*)d_in[4];
  const float* aw2    = (const float*)d_in[5];
  const float* ab2    = (const float*)d_in[6];
  float* out = (float*)d_out;

  char* ws = (char*)d_ws;
  unsigned short* xt   = (unsigned short*)ws;                        // 69,222,400 B
  unsigned short* aggw = (unsigned short*)(ws + 69222400);           //  4,718,592 B
  float* rowsum        = (float*)(ws + 69222400 + 4718592);          //  1,048,576 B
  float* attn          = (float*)(ws + 69222400 + 4718592 + 1048576);         // 256 B
  float* aggb          = (float*)(ws + 69222400 + 4718592 + 1048576 + 256);   // 8 KB

  hipLaunchKernelGGL(k_border, dim3(33, 16), dim3(256), 0, stream, xt);
  hipLaunchKernelGGL(k_transpose, dim3(128, 16), dim3(256), 0, stream, x, xt, rowsum);
  hipLaunchKernelGGL(k_attn, dim3(16), dim3(128), 0, stream,
                     rowsum, aw1, ab1, aw2, ab2, bias, attn, aggb);
  hipLaunchKernelGGL(k_aggw, dim3(9216), dim3(256), 0, stream, weight, attn, aggw);
  hipLaunchKernelGGL(k_conv, dim3(2048), dim3(256), 0, stream, xt, aggw, aggb, out);
}